// Round 6
// baseline (249.193 us; speedup 1.0000x reference)
//
#include <hip/hip_runtime.h>

#define BATCH 8
#define NBOX 2000
#define NCLS 81
#define NPAD 2048
#define MAX_OUT 300
#define SCORE_T 0.05f
#define IOU_T 0.5f
#define MASK_WORDS 64   /* 2048 cols / 32 bits */

// ---- ws byte offsets ----
#define WS_BOXES   0          // float4[16000]           256000
#define WS_SCORES  256000     // float [16000]            64000
#define WS_SKEY    320000     // u64   [8*2048]          131072
#define WS_SBOX    451072     // float4[8*2048]          262144
#define WS_LARR    713216     // int[8]                      32
#define WS_MASK    786432     // uint[8*2048*64]        4194304  (end ~4.98 MB)

// ---------------- prep: softmax fg score/cls + box regression ----------------
__global__ void prep_kernel(const float* __restrict__ deltas,
                            const float* __restrict__ logits,
                            const float* __restrict__ proposals,
                            float4* __restrict__ boxes_out,
                            float* __restrict__ scores_out,
                            int* __restrict__ Larr) {
    int bn = blockIdx.x * blockDim.x + threadIdx.x;
    if (bn < BATCH) Larr[bn] = 0;           // zero before rank_kernel's atomicMax
    if (bn >= BATCH * NBOX) return;

    const float* l = logits + (long)bn * NCLS;

    float M = l[0];
    #pragma unroll 4
    for (int c = 1; c < NCLS; ++c) M = fmaxf(M, l[c]);

    float S = 0.0f;
    float bl = -3.0e38f; int bc = 1;
    #pragma unroll 4
    for (int c = 0; c < NCLS; ++c) {
        float v = l[c];
        S += expf(v - M);
        if (c >= 1 && v > bl) { bl = v; bc = c; }
    }
    float score = expf(bl - M) / S;

    const float* p = proposals + (long)bn * 5;
    float y1 = p[0], x1 = p[1], y2 = p[2], x2 = p[3];
    float h = y2 - y1, w = x2 - x1;
    float cy = (y2 + y1) * 0.5f, cx = (x2 + x1) * 0.5f;

    const float* d = deltas + ((long)bn * NCLS + bc) * 4;
    float d0 = d[0] * 0.1f, d1 = d[1] * 0.1f, d2 = d[2] * 0.2f, d3 = d[3] * 0.2f;

    cy = cy + d0 * h;
    cx = cx + d1 * w;
    h = h * expf(d2);
    w = w * expf(d3);

    boxes_out[bn] = make_float4(cy - h * 0.5f, cx - w * 0.5f,
                                cy + h * 0.5f, cx + w * 0.5f);
    scores_out[bn] = score;
}

// ---- rank: stable descending sort via direct rank (keys unique) + scatter ----
__global__ __launch_bounds__(256) void rank_kernel(
        const float* __restrict__ scores,
        const float4* __restrict__ boxes,
        unsigned long long* __restrict__ skey,
        float4* __restrict__ sbox,
        int* __restrict__ Larr) {
    int bid = blockIdx.x;
    int b = bid & 7, rb = bid >> 3;      // batch = bid%8 -> XCD locality
    int t = threadIdx.x;

    __shared__ unsigned long long s_key[NPAD + 16];
    __shared__ int s_part[64][4];

    for (int c = t; c < NPAD; c += 256) {
        unsigned int bits = 0u;
        if (c < NBOX) bits = __float_as_uint(scores[b * NBOX + c]);
        s_key[c + (c >> 7)] =
            ((unsigned long long)bits << 32) |
            (unsigned long long)(0xFFFFFFFFu - (unsigned)c);
    }
    __syncthreads();

    int own = rb * 64 + (t >> 2);
    int seg = t & 3;
    unsigned long long mykey = s_key[own + (own >> 7)];
    int cnt = 0;
    int cbase = seg * 512;
    #pragma unroll 4
    for (int j = 0; j < 512; ++j) {
        int c = cbase + j;
        cnt += (s_key[c + (c >> 7)] > mykey) ? 1 : 0;
    }
    s_part[t >> 2][seg] = cnt;
    __syncthreads();

    if (t < 64) {
        int own2 = rb * 64 + t;
        unsigned long long key = s_key[own2 + (own2 >> 7)];
        int rank = s_part[t][0] + s_part[t][1] + s_part[t][2] + s_part[t][3];
        skey[b * NPAD + rank] = key;
        unsigned int orig = 0xFFFFFFFFu - (unsigned int)key;
        float4 bx = make_float4(0.f, 0.f, 0.f, 0.f);
        if (orig < NBOX) bx = boxes[b * NBOX + orig];
        sbox[b * NPAD + rank] = bx;
        float sc = __uint_as_float((unsigned int)(key >> 32));
        if (sc > SCORE_T) atomicMax(&Larr[b], rank + 1);
    }
}

// ---- mask: UPPER-TRIANGLE pairwise suppression bitmatrix ----
// Commits happen in ascending rank, so when row r is applied all cols <= r are
// already dead -> words whose max col <= r may hold garbage (left unwritten).
// Thread map: wave = 64 consecutive rows x one 16-word segment -> whole-wave skip.
__global__ __launch_bounds__(256) void mask_kernel(
        const float4* __restrict__ sbox,
        unsigned int* __restrict__ mask) {
    int bid = blockIdx.x;
    int b = bid & 7, rb = bid >> 3;      // batch = bid%8 -> same XCD as walk block b
    int t = threadIdx.x;

    __shared__ float4 s_bx[NPAD + 16];

    for (int c = t; c < NPAD; c += 256)
        s_bx[c + (c >> 7)] = sbox[b * NPAD + c];
    __syncthreads();

    int r   = rb * 64 + (t & 63);        // row: lanes of a wave = 64 consecutive rows
    int seg = t >> 6;                    // word segment 0..3 (16 words each)
    float4 rbx = s_bx[r + (r >> 7)];
    float rar = (rbx.z - rbx.x) * (rbx.w - rbx.y);
    unsigned int* out = mask + (((size_t)(b * NPAD + r)) << 6);

    for (int w = 0; w < 16; ++w) {
        int wi = seg * 16 + w;
        if ((wi << 5) + 31 <= r) continue;   // word entirely at/below diagonal
        unsigned int bits = 0u;
        int colbase = wi << 5;
        #pragma unroll 8
        for (int c2 = 0; c2 < 32; ++c2) {
            int col = colbase + c2;
            float4 ob = s_bx[col + (col >> 7)];
            float oa = (ob.z - ob.x) * (ob.w - ob.y);
            float yy1 = fmaxf(rbx.x, ob.x), xx1 = fmaxf(rbx.y, ob.y);
            float yy2 = fminf(rbx.z, ob.z), xx2 = fminf(rbx.w, ob.w);
            float inter = fmaxf(yy2 - yy1, 0.f) * fmaxf(xx2 - xx1, 0.f);
            float iou = inter / (rar + oa - inter + 1e-8f);   // IEEE fdiv: exact vs ref
            bits |= (iou > IOU_T) ? (1u << c2) : 0u;
        }
        out[wi] = bits;
    }
}

// ---- walk: greedy over alive bitvector, 4-deep row speculation, fused output ----
__global__ __launch_bounds__(64) void walk_kernel(
        const int* __restrict__ Larr,
        const unsigned int* __restrict__ mask,
        const unsigned long long* __restrict__ skey,
        const float4* __restrict__ sbox,
        const float* __restrict__ logits,
        float* __restrict__ out) {
    int b = blockIdx.x;
    int lane = threadIdx.x;

    __shared__ int s_kl[MAX_OUT];

    int L = Larr[b];
    int base = lane << 5;
    int nset = L - base;
    nset = nset < 0 ? 0 : (nset > 32 ? 32 : nset);
    unsigned int alive = (nset >= 32) ? 0xFFFFFFFFu
                        : ((nset <= 0) ? 0u : ((1u << nset) - 1u));

    const unsigned int* M = mask + ((size_t)b * NPAD) * MASK_WORDS;
    int kept = 0;

#define FIND_NEXT(rd)                                                        \
    {                                                                        \
        unsigned long long _bal = __ballot(a2 != 0u);                        \
        if (_bal) {                                                          \
            int _w = (int)__builtin_ctzll(_bal);                             \
            unsigned int _aw =                                               \
                (unsigned int)__builtin_amdgcn_readlane((int)a2, _w);        \
            rd = (_w << 5) + (int)__builtin_ctz(_aw);                        \
            if (lane == _w) a2 &= ~(1u << (rd & 31));                        \
        }                                                                    \
    }

    while (kept < MAX_OUT) {
        unsigned int a2 = alive;
        int r0 = -1, r1 = -1, r2 = -1, r3 = -1;
        FIND_NEXT(r0);
        if (r0 < 0) break;
        FIND_NEXT(r1);
        FIND_NEXT(r2);
        FIND_NEXT(r3);

        // issue all speculative row loads together (latencies overlap)
        unsigned int row0 = M[((size_t)r0 << 6) + lane];
        unsigned int row1 = (r1 >= 0) ? M[((size_t)r1 << 6) + lane] : 0u;
        unsigned int row2 = (r2 >= 0) ? M[((size_t)r2 << 6) + lane] : 0u;
        unsigned int row3 = (r3 >= 0) ? M[((size_t)r3 << 6) + lane] : 0u;

        // commit r0 unconditionally
        if (lane == 0) s_kl[kept] = r0;
        kept++;
        alive &= ~row0;
        if (lane == (r0 >> 5)) alive &= ~(1u << (r0 & 31));

        // commit r1..r3 if still alive (exact greedy: ascending rank order)
        if (r1 >= 0 && kept < MAX_OUT) {
            unsigned int av = (unsigned int)__builtin_amdgcn_readlane((int)alive, r1 >> 5);
            if (av & (1u << (r1 & 31))) {
                if (lane == 0) s_kl[kept] = r1;
                kept++;
                alive &= ~row1;
                if (lane == (r1 >> 5)) alive &= ~(1u << (r1 & 31));
            }
        }
        if (r2 >= 0 && kept < MAX_OUT) {
            unsigned int av = (unsigned int)__builtin_amdgcn_readlane((int)alive, r2 >> 5);
            if (av & (1u << (r2 & 31))) {
                if (lane == 0) s_kl[kept] = r2;
                kept++;
                alive &= ~row2;
                if (lane == (r2 >> 5)) alive &= ~(1u << (r2 & 31));
            }
        }
        if (r3 >= 0 && kept < MAX_OUT) {
            unsigned int av = (unsigned int)__builtin_amdgcn_readlane((int)alive, r3 >> 5);
            if (av & (1u << (r3 & 31))) {
                if (lane == 0) s_kl[kept] = r3;
                kept++;
                alive &= ~row3;
                if (lane == (r3 >> 5)) alive &= ~(1u << (r3 & 31));
            }
        }
    }
#undef FIND_NEXT

    __syncthreads();
    int kc = kept;   // uniform across the wave

    // ---- fused output writes (zeros beyond kc) ----
    float* ob = out + (long)b * MAX_OUT * 5;
    for (int e = lane; e < MAX_OUT * 5; e += 64) {
        int k = e / 5, c = e - 5 * k;
        float v = 0.f;
        if (k < kc) {
            if (c == 4) v = 1.f;
            else {
                float4 bx = sbox[b * NPAD + s_kl[k]];
                v = (c == 0) ? bx.x : (c == 1) ? bx.y : (c == 2) ? bx.z : bx.w;
            }
        }
        ob[e] = v;
    }
    float* os = out + (long)BATCH * MAX_OUT * 5 + (long)b * MAX_OUT * 2;
    for (int e = lane; e < MAX_OUT * 2; e += 64) {
        int k = e >> 1, c = e & 1;
        float v = 0.f;
        if (k < kc) {
            if (c) v = 1.f;
            else v = __uint_as_float(
                     (unsigned int)(skey[b * NPAD + s_kl[k]] >> 32));
        }
        os[e] = v;
    }
    float* ol = out + (long)BATCH * MAX_OUT * (5 + 2) + (long)b * MAX_OUT * NCLS;
    for (int k = 0; k < MAX_OUT; ++k) {
        if (k < kc) {
            unsigned long long key = skey[b * NPAD + s_kl[k]];
            unsigned int orig = 0xFFFFFFFFu - (unsigned int)key;
            const float* src = logits + ((long)b * NBOX + orig) * NCLS;
            ol[k * NCLS + lane] = src[lane];
            if (lane < NCLS - 64) ol[k * NCLS + 64 + lane] = src[64 + lane];
        } else {
            ol[k * NCLS + lane] = 0.f;
            if (lane < NCLS - 64) ol[k * NCLS + 64 + lane] = 0.f;
        }
    }
}

extern "C" void kernel_launch(void* const* d_in, const int* in_sizes, int n_in,
                              void* d_out, int out_size, void* d_ws, size_t ws_size,
                              hipStream_t stream) {
    const float* deltas    = (const float*)d_in[0];
    const float* logits    = (const float*)d_in[1];
    const float* proposals = (const float*)d_in[2];
    float* out = (float*)d_out;

    char* ws = (char*)d_ws;
    float4* ws_boxes  = (float4*)(ws + WS_BOXES);
    float*  ws_scores = (float*)(ws + WS_SCORES);
    unsigned long long* ws_skey = (unsigned long long*)(ws + WS_SKEY);
    float4* ws_sbox   = (float4*)(ws + WS_SBOX);
    int*    ws_Larr   = (int*)(ws + WS_LARR);
    unsigned int* ws_mask = (unsigned int*)(ws + WS_MASK);

    prep_kernel<<<(BATCH * NBOX + 255) / 256, 256, 0, stream>>>(
        deltas, logits, proposals, ws_boxes, ws_scores, ws_Larr);
    rank_kernel<<<BATCH * (NPAD / 64), 256, 0, stream>>>(
        ws_scores, ws_boxes, ws_skey, ws_sbox, ws_Larr);
    mask_kernel<<<BATCH * (NPAD / 64), 256, 0, stream>>>(
        ws_sbox, ws_mask);
    walk_kernel<<<BATCH, 64, 0, stream>>>(
        ws_Larr, ws_mask, ws_skey, ws_sbox, logits, out);
}

// Round 7
// 163.175 us; speedup vs baseline: 1.5272x; 1.5272x over previous
//
#include <hip/hip_runtime.h>

#define BATCH 8
#define NBOX 2000
#define NCLS 81
#define NPAD 2048
#define MAX_OUT 300
#define SCORE_T 0.05f
#define IOU_T 0.5f
#define MASK_WORDS 64   /* 2048 cols / 32 bits */

// ---- ws byte offsets ----
#define WS_BOXES   0          // float4[16000]           256000
#define WS_SCORES  256000     // float [16000]            64000
#define WS_SKEY    320000     // u64   [8*2048]          131072
#define WS_SBOX    451072     // float4[8*2048]          262144
#define WS_LARR    713216     // int[8]                      32
#define WS_KLIST   713248     // int[8*300]                9600
#define WS_KCOUNT  722848     // int[8]                      32
#define WS_MASK    786432     // uint[8*2048*64]        4194304  (end ~4.98 MB)

// ---------------- prep: softmax fg score/cls + box regression ----------------
__global__ void prep_kernel(const float* __restrict__ deltas,
                            const float* __restrict__ logits,
                            const float* __restrict__ proposals,
                            float4* __restrict__ boxes_out,
                            float* __restrict__ scores_out,
                            int* __restrict__ Larr) {
    int bn = blockIdx.x * blockDim.x + threadIdx.x;
    if (bn < BATCH) Larr[bn] = 0;           // zero before rank_kernel's atomicMax
    if (bn >= BATCH * NBOX) return;

    const float* l = logits + (long)bn * NCLS;

    float M = l[0];
    #pragma unroll 4
    for (int c = 1; c < NCLS; ++c) M = fmaxf(M, l[c]);

    float S = 0.0f;
    float bl = -3.0e38f; int bc = 1;
    #pragma unroll 4
    for (int c = 0; c < NCLS; ++c) {
        float v = l[c];
        S += expf(v - M);
        if (c >= 1 && v > bl) { bl = v; bc = c; }
    }
    float score = expf(bl - M) / S;

    const float* p = proposals + (long)bn * 5;
    float y1 = p[0], x1 = p[1], y2 = p[2], x2 = p[3];
    float h = y2 - y1, w = x2 - x1;
    float cy = (y2 + y1) * 0.5f, cx = (x2 + x1) * 0.5f;

    const float* d = deltas + ((long)bn * NCLS + bc) * 4;
    float d0 = d[0] * 0.1f, d1 = d[1] * 0.1f, d2 = d[2] * 0.2f, d3 = d[3] * 0.2f;

    cy = cy + d0 * h;
    cx = cx + d1 * w;
    h = h * expf(d2);
    w = w * expf(d3);

    boxes_out[bn] = make_float4(cy - h * 0.5f, cx - w * 0.5f,
                                cy + h * 0.5f, cx + w * 0.5f);
    scores_out[bn] = score;
}

// ---- rank: stable descending sort via direct rank (keys unique) + scatter ----
__global__ __launch_bounds__(256) void rank_kernel(
        const float* __restrict__ scores,
        const float4* __restrict__ boxes,
        unsigned long long* __restrict__ skey,
        float4* __restrict__ sbox,
        int* __restrict__ Larr) {
    int bid = blockIdx.x;
    int b = bid & 7, rb = bid >> 3;      // batch = bid%8 -> XCD locality
    int t = threadIdx.x;

    __shared__ unsigned long long s_key[NPAD + 16];
    __shared__ int s_part[64][4];

    for (int c = t; c < NPAD; c += 256) {
        unsigned int bits = 0u;
        if (c < NBOX) bits = __float_as_uint(scores[b * NBOX + c]);
        s_key[c + (c >> 7)] =
            ((unsigned long long)bits << 32) |
            (unsigned long long)(0xFFFFFFFFu - (unsigned)c);
    }
    __syncthreads();

    int own = rb * 64 + (t >> 2);
    int seg = t & 3;
    unsigned long long mykey = s_key[own + (own >> 7)];
    int cnt = 0;
    int cbase = seg * 512;
    #pragma unroll 4
    for (int j = 0; j < 512; ++j) {
        int c = cbase + j;
        cnt += (s_key[c + (c >> 7)] > mykey) ? 1 : 0;
    }
    s_part[t >> 2][seg] = cnt;
    __syncthreads();

    if (t < 64) {
        int own2 = rb * 64 + t;
        unsigned long long key = s_key[own2 + (own2 >> 7)];
        int rank = s_part[t][0] + s_part[t][1] + s_part[t][2] + s_part[t][3];
        skey[b * NPAD + rank] = key;
        unsigned int orig = 0xFFFFFFFFu - (unsigned int)key;
        float4 bx = make_float4(0.f, 0.f, 0.f, 0.f);
        if (orig < NBOX) bx = boxes[b * NBOX + orig];
        sbox[b * NPAD + rank] = bx;
        float sc = __uint_as_float((unsigned int)(key >> 32));
        if (sc > SCORE_T) atomicMax(&Larr[b], rank + 1);
    }
}

// ---- mask: UPPER-TRIANGLE pairwise suppression bitmatrix ----
// Walk commits in ascending rank, so when row r is applied all cols <= r are
// already dead -> words whose max col <= r are never written OR read.
__global__ __launch_bounds__(256) void mask_kernel(
        const float4* __restrict__ sbox,
        unsigned int* __restrict__ mask) {
    int bid = blockIdx.x;
    int b = bid & 7, rb = bid >> 3;      // batch = bid%8 -> same XCD as walk block b
    int t = threadIdx.x;

    __shared__ float4 s_bx[NPAD + 16];

    for (int c = t; c < NPAD; c += 256)
        s_bx[c + (c >> 7)] = sbox[b * NPAD + c];
    __syncthreads();

    int r   = rb * 64 + (t & 63);        // row: lanes of a wave = 64 consecutive rows
    int seg = t >> 6;                    // word segment 0..3 (16 words each)
    float4 rbx = s_bx[r + (r >> 7)];
    float rar = (rbx.z - rbx.x) * (rbx.w - rbx.y);
    unsigned int* outp = mask + (((size_t)(b * NPAD + r)) << 6);

    for (int w = 0; w < 16; ++w) {
        int wi = seg * 16 + w;
        if ((wi << 5) + 31 <= r) continue;   // word entirely at/below diagonal
        unsigned int bits = 0u;
        int colbase = wi << 5;
        #pragma unroll 8
        for (int c2 = 0; c2 < 32; ++c2) {
            int col = colbase + c2;
            float4 ob = s_bx[col + (col >> 7)];
            float oa = (ob.z - ob.x) * (ob.w - ob.y);
            float yy1 = fmaxf(rbx.x, ob.x), xx1 = fmaxf(rbx.y, ob.y);
            float yy2 = fminf(rbx.z, ob.z), xx2 = fminf(rbx.w, ob.w);
            float inter = fmaxf(yy2 - yy1, 0.f) * fmaxf(xx2 - xx1, 0.f);
            float iou = inter / (rar + oa - inter + 1e-8f);   // IEEE fdiv: exact vs ref
            bits |= (iou > IOU_T) ? (1u << c2) : 0u;
        }
        outp[wi] = bits;
    }
}

// ---- walk: greedy over alive bitvector, 8-deep row speculation ----
// Invariant: r0..r7 are the first alive candidates in ascending rank, so when
// row_rd is applied every col < rd is already dead -> below-diagonal words are
// never needed (lanes with max col <= rd substitute 0 and issue NO load).
__global__ __launch_bounds__(64) void walk_kernel(
        const int* __restrict__ Larr,
        const unsigned int* __restrict__ mask,
        int* __restrict__ klist,
        int* __restrict__ kcount) {
    int b = blockIdx.x;
    int lane = threadIdx.x;

    int L = Larr[b];
    int nset = L - (lane << 5);
    nset = nset < 0 ? 0 : (nset > 32 ? 32 : nset);
    unsigned int alive = (nset >= 32) ? 0xFFFFFFFFu
                        : ((nset <= 0) ? 0u : ((1u << nset) - 1u));

    const unsigned int* M = mask + ((size_t)b * NPAD) * MASK_WORDS;
    int* kl = klist + b * MAX_OUT;
    int kept = 0;
    int lanehi = (lane << 5) + 31;       // max col covered by this lane's word

#define FIND_NEXT(rd)                                                        \
    {                                                                        \
        unsigned long long _bal = __ballot(a2 != 0u);                        \
        if (_bal) {                                                          \
            int _w = (int)__builtin_ctzll(_bal);                             \
            unsigned int _aw =                                               \
                (unsigned int)__builtin_amdgcn_readlane((int)a2, _w);        \
            rd = (_w << 5) + (int)__builtin_ctz(_aw);                        \
            if (lane == _w) a2 &= ~(1u << (rd & 31));                        \
        }                                                                    \
    }
#define LOAD_ROW(rowd, rd)                                                   \
    unsigned int rowd = (rd >= 0 && lanehi > rd)                             \
        ? M[((size_t)rd << 6) + lane] : 0u;
#define COMMIT(rd, rowd)                                                     \
    if (rd >= 0 && kept < MAX_OUT) {                                         \
        unsigned int _av =                                                   \
            (unsigned int)__builtin_amdgcn_readlane((int)alive, rd >> 5);    \
        if (_av & (1u << (rd & 31))) {                                       \
            if (lane == 0) kl[kept] = rd;                                    \
            kept++;                                                          \
            alive &= ~rowd;                                                  \
            if (lane == (rd >> 5)) alive &= ~(1u << (rd & 31));              \
        }                                                                    \
    }

    while (kept < MAX_OUT) {
        unsigned int a2 = alive;
        int r0 = -1, r1 = -1, r2 = -1, r3 = -1,
            r4 = -1, r5 = -1, r6 = -1, r7 = -1;
        FIND_NEXT(r0);
        if (r0 < 0) break;
        FIND_NEXT(r1); FIND_NEXT(r2); FIND_NEXT(r3);
        FIND_NEXT(r4); FIND_NEXT(r5); FIND_NEXT(r6); FIND_NEXT(r7);

        // issue all speculative row loads together (latencies overlap)
        LOAD_ROW(row0, r0); LOAD_ROW(row1, r1);
        LOAD_ROW(row2, r2); LOAD_ROW(row3, r3);
        LOAD_ROW(row4, r4); LOAD_ROW(row5, r5);
        LOAD_ROW(row6, r6); LOAD_ROW(row7, r7);

        // r0 always commits (it is the global argmax of what's alive)
        if (lane == 0) kl[kept] = r0;
        kept++;
        alive &= ~row0;
        if (lane == (r0 >> 5)) alive &= ~(1u << (r0 & 31));

        COMMIT(r1, row1); COMMIT(r2, row2); COMMIT(r3, row3);
        COMMIT(r4, row4); COMMIT(r5, row5); COMMIT(r6, row6);
        COMMIT(r7, row7);
    }
#undef FIND_NEXT
#undef LOAD_ROW
#undef COMMIT

    if (lane == 0) kcount[b] = kept;
}

// ---------------- outputs: parallel gather + zero-fill ----------------
__global__ void out_kernel(const unsigned long long* __restrict__ skey,
                           const float4* __restrict__ sbox,
                           const int* __restrict__ klist,
                           const int* __restrict__ kcount,
                           const float* __restrict__ logits,
                           float* __restrict__ out) {
    int idx = blockIdx.x * blockDim.x + threadIdx.x;
    const int NB = BATCH * MAX_OUT * 5;        // 12000
    const int NS = BATCH * MAX_OUT * 2;        // 4800
    const int NL = BATCH * MAX_OUT * NCLS;     // 194400
    if (idx >= NB + NS + NL) return;

    if (idx < NB) {
        int b = idx / (MAX_OUT * 5);
        int rem = idx - b * (MAX_OUT * 5);
        int k = rem / 5, c = rem - 5 * k;
        float v = 0.f;
        if (k < kcount[b]) {
            if (c == 4) v = 1.f;
            else {
                float4 bx = sbox[b * NPAD + klist[b * MAX_OUT + k]];
                v = (c == 0) ? bx.x : (c == 1) ? bx.y : (c == 2) ? bx.z : bx.w;
            }
        }
        out[idx] = v;
    } else if (idx < NB + NS) {
        int j = idx - NB;
        int b = j / (MAX_OUT * 2);
        int rem = j - b * (MAX_OUT * 2);
        int k = rem >> 1, c = rem & 1;
        float v = 0.f;
        if (k < kcount[b]) {
            if (c) v = 1.f;
            else {
                unsigned long long key = skey[b * NPAD + klist[b * MAX_OUT + k]];
                v = __uint_as_float((unsigned int)(key >> 32));
            }
        }
        out[idx] = v;
    } else {
        int j = idx - NB - NS;
        int b = j / (MAX_OUT * NCLS);
        int rem = j - b * (MAX_OUT * NCLS);
        int k = rem / NCLS, c = rem - NCLS * k;
        float v = 0.f;
        if (k < kcount[b]) {
            unsigned long long key = skey[b * NPAD + klist[b * MAX_OUT + k]];
            unsigned int orig = 0xFFFFFFFFu - (unsigned int)key;
            v = logits[((long)b * NBOX + orig) * NCLS + c];
        }
        out[idx] = v;
    }
}

extern "C" void kernel_launch(void* const* d_in, const int* in_sizes, int n_in,
                              void* d_out, int out_size, void* d_ws, size_t ws_size,
                              hipStream_t stream) {
    const float* deltas    = (const float*)d_in[0];
    const float* logits    = (const float*)d_in[1];
    const float* proposals = (const float*)d_in[2];
    float* out = (float*)d_out;

    char* ws = (char*)d_ws;
    float4* ws_boxes  = (float4*)(ws + WS_BOXES);
    float*  ws_scores = (float*)(ws + WS_SCORES);
    unsigned long long* ws_skey = (unsigned long long*)(ws + WS_SKEY);
    float4* ws_sbox   = (float4*)(ws + WS_SBOX);
    int*    ws_Larr   = (int*)(ws + WS_LARR);
    int*    ws_klist  = (int*)(ws + WS_KLIST);
    int*    ws_kcount = (int*)(ws + WS_KCOUNT);
    unsigned int* ws_mask = (unsigned int*)(ws + WS_MASK);

    prep_kernel<<<(BATCH * NBOX + 255) / 256, 256, 0, stream>>>(
        deltas, logits, proposals, ws_boxes, ws_scores, ws_Larr);
    rank_kernel<<<BATCH * (NPAD / 64), 256, 0, stream>>>(
        ws_scores, ws_boxes, ws_skey, ws_sbox, ws_Larr);
    mask_kernel<<<BATCH * (NPAD / 64), 256, 0, stream>>>(
        ws_sbox, ws_mask);
    walk_kernel<<<BATCH, 64, 0, stream>>>(
        ws_Larr, ws_mask, ws_klist, ws_kcount);
    int total_out = BATCH * MAX_OUT * (5 + 2 + NCLS);
    out_kernel<<<(total_out + 255) / 256, 256, 0, stream>>>(
        ws_skey, ws_sbox, ws_klist, ws_kcount, logits, out);
}

// Round 8
// 137.261 us; speedup vs baseline: 1.8155x; 1.1888x over previous
//
#include <hip/hip_runtime.h>

#define BATCH 8
#define NBOX 2000
#define NCLS 81
#define NPAD 2048
#define MAX_OUT 300
#define SCORE_T 0.05f
#define IOU_T 0.5f
#define MASK_WORDS 64   /* 2048 cols / 32 bits */

// ---- ws byte offsets ----
#define WS_BOXES   0          // float4[16000]           256000
#define WS_SCORES  256000     // float [16000]            64000
#define WS_SKEY    320000     // u64   [8*2048]          131072
#define WS_SBOX    451072     // float4[8*2048]          262144
#define WS_LARR    713216     // int[8]                      32
#define WS_KLIST   713248     // int[8*300]                9600
#define WS_KCOUNT  722848     // int[8]                      32
#define WS_MASK    786432     // uint[8*2048*64]        4194304  (end ~4.98 MB)

// ---------------- prep: softmax fg score/cls + box regression ----------------
__global__ void prep_kernel(const float* __restrict__ deltas,
                            const float* __restrict__ logits,
                            const float* __restrict__ proposals,
                            float4* __restrict__ boxes_out,
                            float* __restrict__ scores_out,
                            int* __restrict__ Larr) {
    int bn = blockIdx.x * blockDim.x + threadIdx.x;
    if (bn < BATCH) Larr[bn] = 0;           // zero before rank_kernel's atomicMax
    if (bn >= BATCH * NBOX) return;

    const float* l = logits + (long)bn * NCLS;

    float M = l[0];
    #pragma unroll 4
    for (int c = 1; c < NCLS; ++c) M = fmaxf(M, l[c]);

    float S = 0.0f;
    float bl = -3.0e38f; int bc = 1;
    #pragma unroll 4
    for (int c = 0; c < NCLS; ++c) {
        float v = l[c];
        S += expf(v - M);
        if (c >= 1 && v > bl) { bl = v; bc = c; }
    }
    float score = expf(bl - M) / S;

    const float* p = proposals + (long)bn * 5;
    float y1 = p[0], x1 = p[1], y2 = p[2], x2 = p[3];
    float h = y2 - y1, w = x2 - x1;
    float cy = (y2 + y1) * 0.5f, cx = (x2 + x1) * 0.5f;

    const float* d = deltas + ((long)bn * NCLS + bc) * 4;
    float d0 = d[0] * 0.1f, d1 = d[1] * 0.1f, d2 = d[2] * 0.2f, d3 = d[3] * 0.2f;

    cy = cy + d0 * h;
    cx = cx + d1 * w;
    h = h * expf(d2);
    w = w * expf(d3);

    boxes_out[bn] = make_float4(cy - h * 0.5f, cx - w * 0.5f,
                                cy + h * 0.5f, cx + w * 0.5f);
    scores_out[bn] = score;
}

// ---- rank: stable descending sort via direct rank (keys unique) + scatter ----
__global__ __launch_bounds__(256) void rank_kernel(
        const float* __restrict__ scores,
        const float4* __restrict__ boxes,
        unsigned long long* __restrict__ skey,
        float4* __restrict__ sbox,
        int* __restrict__ Larr) {
    int bid = blockIdx.x;
    int b = bid & 7, rb = bid >> 3;      // batch = bid%8 -> XCD locality
    int t = threadIdx.x;

    __shared__ unsigned long long s_key[NPAD + 16];
    __shared__ int s_part[64][4];

    for (int c = t; c < NPAD; c += 256) {
        unsigned int bits = 0u;
        if (c < NBOX) bits = __float_as_uint(scores[b * NBOX + c]);
        s_key[c + (c >> 7)] =
            ((unsigned long long)bits << 32) |
            (unsigned long long)(0xFFFFFFFFu - (unsigned)c);
    }
    __syncthreads();

    int own = rb * 64 + (t >> 2);
    int seg = t & 3;
    unsigned long long mykey = s_key[own + (own >> 7)];
    int cnt = 0;
    int cbase = seg * 512;
    #pragma unroll 4
    for (int j = 0; j < 512; ++j) {
        int c = cbase + j;
        cnt += (s_key[c + (c >> 7)] > mykey) ? 1 : 0;
    }
    s_part[t >> 2][seg] = cnt;
    __syncthreads();

    if (t < 64) {
        int own2 = rb * 64 + t;
        unsigned long long key = s_key[own2 + (own2 >> 7)];
        int rank = s_part[t][0] + s_part[t][1] + s_part[t][2] + s_part[t][3];
        skey[b * NPAD + rank] = key;
        unsigned int orig = 0xFFFFFFFFu - (unsigned int)key;
        float4 bx = make_float4(0.f, 0.f, 0.f, 0.f);
        if (orig < NBOX) bx = boxes[b * NBOX + orig];
        sbox[b * NPAD + rank] = bx;
        float sc = __uint_as_float((unsigned int)(key >> 32));
        if (sc > SCORE_T) atomicMax(&Larr[b], rank + 1);
    }
}

// ---- mask: upper-triangle compute, FULL-row stores (below-diag words = 0) ----
// Walk commits in ascending rank, so cols <= r are dead when row r is applied;
// below-diagonal words carry no information -> store 0 (keeps rows fully valid
// and L2-resident so the walk can load unconditionally), skip their IoU math.
__global__ __launch_bounds__(256) void mask_kernel(
        const float4* __restrict__ sbox,
        unsigned int* __restrict__ mask) {
    int bid = blockIdx.x;
    int b = bid & 7, rb = bid >> 3;      // batch = bid%8 -> same XCD as walk block b
    int t = threadIdx.x;

    __shared__ float4 s_bx[NPAD + 16];

    for (int c = t; c < NPAD; c += 256)
        s_bx[c + (c >> 7)] = sbox[b * NPAD + c];
    __syncthreads();

    int r   = rb * 64 + (t & 63);        // row: lanes of a wave = 64 consecutive rows
    int seg = t >> 6;                    // word segment 0..3 (16 words each)
    float4 rbx = s_bx[r + (r >> 7)];
    float rar = (rbx.z - rbx.x) * (rbx.w - rbx.y);
    unsigned int* outp = mask + (((size_t)(b * NPAD + r)) << 6);

    for (int w = 0; w < 16; ++w) {
        int wi = seg * 16 + w;
        unsigned int bits = 0u;
        if ((wi << 5) + 31 > r) {        // word has at least one col above diagonal
            int colbase = wi << 5;
            #pragma unroll 8
            for (int c2 = 0; c2 < 32; ++c2) {
                int col = colbase + c2;
                float4 ob = s_bx[col + (col >> 7)];
                float oa = (ob.z - ob.x) * (ob.w - ob.y);
                float yy1 = fmaxf(rbx.x, ob.x), xx1 = fmaxf(rbx.y, ob.y);
                float yy2 = fminf(rbx.z, ob.z), xx2 = fminf(rbx.w, ob.w);
                float inter = fmaxf(yy2 - yy1, 0.f) * fmaxf(xx2 - xx1, 0.f);
                float iou = inter / (rar + oa - inter + 1e-8f);  // IEEE fdiv: exact vs ref
                bits |= (iou > IOU_T) ? (1u << c2) : 0u;
            }
        }
        outp[wi] = bits;
    }
}

// ---- walk: greedy over alive bitvector, 8-deep speculation, UNCONDITIONAL loads ----
// All 8 row loads issue back-to-back with safe addresses (rd<0 -> reuse r0's row);
// a row is only applied inside a committed rd>=0 branch, so garbage rows are
// never consumed. This lets the 8 L2 latencies overlap instead of serializing.
__global__ __launch_bounds__(64) void walk_kernel(
        const int* __restrict__ Larr,
        const unsigned int* __restrict__ mask,
        int* __restrict__ klist,
        int* __restrict__ kcount) {
    int b = blockIdx.x;
    int lane = threadIdx.x;

    int L = Larr[b];
    int nset = L - (lane << 5);
    nset = nset < 0 ? 0 : (nset > 32 ? 32 : nset);
    unsigned int alive = (nset >= 32) ? 0xFFFFFFFFu
                        : ((nset <= 0) ? 0u : ((1u << nset) - 1u));

    const unsigned int* M = mask + ((size_t)b * NPAD) * MASK_WORDS;
    int* kl = klist + b * MAX_OUT;
    int kept = 0;

#define FIND_NEXT(rd)                                                        \
    {                                                                        \
        unsigned long long _bal = __ballot(a2 != 0u);                        \
        if (_bal) {                                                          \
            int _w = (int)__builtin_ctzll(_bal);                             \
            unsigned int _aw =                                               \
                (unsigned int)__builtin_amdgcn_readlane((int)a2, _w);        \
            rd = (_w << 5) + (int)__builtin_ctz(_aw);                        \
            if (lane == _w) a2 &= ~(1u << (rd & 31));                        \
        }                                                                    \
    }
#define COMMIT(rd, rowd)                                                     \
    if (rd >= 0 && kept < MAX_OUT) {                                         \
        unsigned int _av =                                                   \
            (unsigned int)__builtin_amdgcn_readlane((int)alive, rd >> 5);    \
        if (_av & (1u << (rd & 31))) {                                       \
            if (lane == 0) kl[kept] = rd;                                    \
            kept++;                                                          \
            alive &= ~rowd;                                                  \
            if (lane == (rd >> 5)) alive &= ~(1u << (rd & 31));              \
        }                                                                    \
    }

    while (kept < MAX_OUT) {
        unsigned int a2 = alive;
        int r0 = -1, r1 = -1, r2 = -1, r3 = -1,
            r4 = -1, r5 = -1, r6 = -1, r7 = -1;
        FIND_NEXT(r0);
        if (r0 < 0) break;
        FIND_NEXT(r1); FIND_NEXT(r2); FIND_NEXT(r3);
        FIND_NEXT(r4); FIND_NEXT(r5); FIND_NEXT(r6); FIND_NEXT(r7);

        // safe addresses: missing slots alias r0 (row valid, never applied)
        int s1 = (r1 >= 0) ? r1 : r0;
        int s2 = (r2 >= 0) ? r2 : r0;
        int s3 = (r3 >= 0) ? r3 : r0;
        int s4 = (r4 >= 0) ? r4 : r0;
        int s5 = (r5 >= 0) ? r5 : r0;
        int s6 = (r6 >= 0) ? r6 : r0;
        int s7 = (r7 >= 0) ? r7 : r0;

        // 8 unconditional loads issue together; waits happen at first use
        unsigned int row0 = M[((size_t)r0 << 6) + lane];
        unsigned int row1 = M[((size_t)s1 << 6) + lane];
        unsigned int row2 = M[((size_t)s2 << 6) + lane];
        unsigned int row3 = M[((size_t)s3 << 6) + lane];
        unsigned int row4 = M[((size_t)s4 << 6) + lane];
        unsigned int row5 = M[((size_t)s5 << 6) + lane];
        unsigned int row6 = M[((size_t)s6 << 6) + lane];
        unsigned int row7 = M[((size_t)s7 << 6) + lane];

        // r0 always commits (it is the global argmax of what's alive)
        if (lane == 0) kl[kept] = r0;
        kept++;
        alive &= ~row0;
        if (lane == (r0 >> 5)) alive &= ~(1u << (r0 & 31));

        COMMIT(r1, row1); COMMIT(r2, row2); COMMIT(r3, row3);
        COMMIT(r4, row4); COMMIT(r5, row5); COMMIT(r6, row6);
        COMMIT(r7, row7);
    }
#undef FIND_NEXT
#undef COMMIT

    if (lane == 0) kcount[b] = kept;
}

// ---------------- outputs: parallel gather + zero-fill ----------------
__global__ void out_kernel(const unsigned long long* __restrict__ skey,
                           const float4* __restrict__ sbox,
                           const int* __restrict__ klist,
                           const int* __restrict__ kcount,
                           const float* __restrict__ logits,
                           float* __restrict__ out) {
    int idx = blockIdx.x * blockDim.x + threadIdx.x;
    const int NB = BATCH * MAX_OUT * 5;        // 12000
    const int NS = BATCH * MAX_OUT * 2;        // 4800
    const int NL = BATCH * MAX_OUT * NCLS;     // 194400
    if (idx >= NB + NS + NL) return;

    if (idx < NB) {
        int b = idx / (MAX_OUT * 5);
        int rem = idx - b * (MAX_OUT * 5);
        int k = rem / 5, c = rem - 5 * k;
        float v = 0.f;
        if (k < kcount[b]) {
            if (c == 4) v = 1.f;
            else {
                float4 bx = sbox[b * NPAD + klist[b * MAX_OUT + k]];
                v = (c == 0) ? bx.x : (c == 1) ? bx.y : (c == 2) ? bx.z : bx.w;
            }
        }
        out[idx] = v;
    } else if (idx < NB + NS) {
        int j = idx - NB;
        int b = j / (MAX_OUT * 2);
        int rem = j - b * (MAX_OUT * 2);
        int k = rem >> 1, c = rem & 1;
        float v = 0.f;
        if (k < kcount[b]) {
            if (c) v = 1.f;
            else {
                unsigned long long key = skey[b * NPAD + klist[b * MAX_OUT + k]];
                v = __uint_as_float((unsigned int)(key >> 32));
            }
        }
        out[idx] = v;
    } else {
        int j = idx - NB - NS;
        int b = j / (MAX_OUT * NCLS);
        int rem = j - b * (MAX_OUT * NCLS);
        int k = rem / NCLS, c = rem - NCLS * k;
        float v = 0.f;
        if (k < kcount[b]) {
            unsigned long long key = skey[b * NPAD + klist[b * MAX_OUT + k]];
            unsigned int orig = 0xFFFFFFFFu - (unsigned int)key;
            v = logits[((long)b * NBOX + orig) * NCLS + c];
        }
        out[idx] = v;
    }
}

extern "C" void kernel_launch(void* const* d_in, const int* in_sizes, int n_in,
                              void* d_out, int out_size, void* d_ws, size_t ws_size,
                              hipStream_t stream) {
    const float* deltas    = (const float*)d_in[0];
    const float* logits    = (const float*)d_in[1];
    const float* proposals = (const float*)d_in[2];
    float* out = (float*)d_out;

    char* ws = (char*)d_ws;
    float4* ws_boxes  = (float4*)(ws + WS_BOXES);
    float*  ws_scores = (float*)(ws + WS_SCORES);
    unsigned long long* ws_skey = (unsigned long long*)(ws + WS_SKEY);
    float4* ws_sbox   = (float4*)(ws + WS_SBOX);
    int*    ws_Larr   = (int*)(ws + WS_LARR);
    int*    ws_klist  = (int*)(ws + WS_KLIST);
    int*    ws_kcount = (int*)(ws + WS_KCOUNT);
    unsigned int* ws_mask = (unsigned int*)(ws + WS_MASK);

    prep_kernel<<<(BATCH * NBOX + 255) / 256, 256, 0, stream>>>(
        deltas, logits, proposals, ws_boxes, ws_scores, ws_Larr);
    rank_kernel<<<BATCH * (NPAD / 64), 256, 0, stream>>>(
        ws_scores, ws_boxes, ws_skey, ws_sbox, ws_Larr);
    mask_kernel<<<BATCH * (NPAD / 64), 256, 0, stream>>>(
        ws_sbox, ws_mask);
    walk_kernel<<<BATCH, 64, 0, stream>>>(
        ws_Larr, ws_mask, ws_klist, ws_kcount);
    int total_out = BATCH * MAX_OUT * (5 + 2 + NCLS);
    out_kernel<<<(total_out + 255) / 256, 256, 0, stream>>>(
        ws_skey, ws_sbox, ws_klist, ws_kcount, logits, out);
}

// Round 9
// 117.068 us; speedup vs baseline: 2.1286x; 1.1725x over previous
//
#include <hip/hip_runtime.h>

#define BATCH 8
#define NBOX 2000
#define NCLS 81
#define NPAD 2048
#define MAX_OUT 300
#define SCORE_T 0.05f
#define IOU_T 0.5f
#define MASK_WORDS 64   /* 2048 cols / 32 bits */

// ---- ws byte offsets ----
#define WS_BOXES   0          // float4[16000]           256000
#define WS_SCORES  256000     // float [16000]            64000
#define WS_SKEY    320000     // u64   [8*2048]          131072
#define WS_SBOX    451072     // float4[8*2048]          262144
#define WS_LARR    713216     // int[8]                      32
#define WS_KLIST   713248     // int[8*300]                9600
#define WS_KCOUNT  722848     // int[8]                      32
#define WS_MASK    786432     // uint[8*2048*64]        4194304  (end ~4.98 MB)

// ---------------- prep: softmax fg score/cls + box regression ----------------
__global__ void prep_kernel(const float* __restrict__ deltas,
                            const float* __restrict__ logits,
                            const float* __restrict__ proposals,
                            float4* __restrict__ boxes_out,
                            float* __restrict__ scores_out,
                            int* __restrict__ Larr) {
    int bn = blockIdx.x * blockDim.x + threadIdx.x;
    if (bn < BATCH) Larr[bn] = 0;           // zero before rank_kernel's atomicMax
    if (bn >= BATCH * NBOX) return;

    const float* l = logits + (long)bn * NCLS;

    float M = l[0];
    #pragma unroll 4
    for (int c = 1; c < NCLS; ++c) M = fmaxf(M, l[c]);

    float S = 0.0f;
    float bl = -3.0e38f; int bc = 1;
    #pragma unroll 4
    for (int c = 0; c < NCLS; ++c) {
        float v = l[c];
        S += expf(v - M);
        if (c >= 1 && v > bl) { bl = v; bc = c; }
    }
    float score = expf(bl - M) / S;

    const float* p = proposals + (long)bn * 5;
    float y1 = p[0], x1 = p[1], y2 = p[2], x2 = p[3];
    float h = y2 - y1, w = x2 - x1;
    float cy = (y2 + y1) * 0.5f, cx = (x2 + x1) * 0.5f;

    const float* d = deltas + ((long)bn * NCLS + bc) * 4;
    float d0 = d[0] * 0.1f, d1 = d[1] * 0.1f, d2 = d[2] * 0.2f, d3 = d[3] * 0.2f;

    cy = cy + d0 * h;
    cx = cx + d1 * w;
    h = h * expf(d2);
    w = w * expf(d3);

    boxes_out[bn] = make_float4(cy - h * 0.5f, cx - w * 0.5f,
                                cy + h * 0.5f, cx + w * 0.5f);
    scores_out[bn] = score;
}

// ---- rank: stable descending sort via direct rank, 512 thr (2 waves/SIMD) ----
__global__ __launch_bounds__(512) void rank_kernel(
        const float* __restrict__ scores,
        const float4* __restrict__ boxes,
        unsigned long long* __restrict__ skey,
        float4* __restrict__ sbox,
        int* __restrict__ Larr) {
    int bid = blockIdx.x;
    int b = bid & 7, rb = bid >> 3;      // batch = bid%8 -> XCD locality
    int t = threadIdx.x;

    __shared__ unsigned long long s_key[NPAD + 16];
    __shared__ int s_part[64][8];

    for (int c = t; c < NPAD; c += 512) {
        unsigned int bits = 0u;
        if (c < NBOX) bits = __float_as_uint(scores[b * NBOX + c]);
        s_key[c + (c >> 7)] =
            ((unsigned long long)bits << 32) |
            (unsigned long long)(0xFFFFFFFFu - (unsigned)c);
    }
    __syncthreads();

    int own = rb * 64 + (t >> 3);
    int seg = t & 7;
    unsigned long long mykey = s_key[own + (own >> 7)];
    int cnt = 0;
    int cbase = seg * 256;
    #pragma unroll 4
    for (int j = 0; j < 256; ++j) {
        int c = cbase + j;
        cnt += (s_key[c + (c >> 7)] > mykey) ? 1 : 0;
    }
    s_part[t >> 3][seg] = cnt;
    __syncthreads();

    if (t < 64) {
        int own2 = rb * 64 + t;
        unsigned long long key = s_key[own2 + (own2 >> 7)];
        int rank = s_part[t][0] + s_part[t][1] + s_part[t][2] + s_part[t][3]
                 + s_part[t][4] + s_part[t][5] + s_part[t][6] + s_part[t][7];
        skey[b * NPAD + rank] = key;
        unsigned int orig = 0xFFFFFFFFu - (unsigned int)key;
        float4 bx = make_float4(0.f, 0.f, 0.f, 0.f);
        if (orig < NBOX) bx = boxes[b * NBOX + orig];
        sbox[b * NPAD + rank] = bx;
        float sc = __uint_as_float((unsigned int)(key >> 32));
        if (sc > SCORE_T) atomicMax(&Larr[b], rank + 1);
    }
}

// ---- mask: upper-triangle x alive-prefix compute, full-row stores, 512 thr ----
// Walk only visits rows/cols < L (alive prefix). Rows >= L: whole block may
// exit (never loaded). Words below diagonal or with colbase >= L: store 0
// (loaded by walk's unconditional row reads -> must be valid; bits for
// cols >= L would be harmless anyway since those alive bits start 0).
__global__ __launch_bounds__(512) void mask_kernel(
        const float4* __restrict__ sbox,
        const int* __restrict__ Larr,
        unsigned int* __restrict__ mask) {
    int bid = blockIdx.x;
    int b = bid & 7, rb = bid >> 3;      // batch = bid%8 -> same XCD as walk block b
    int L = Larr[b];
    if (rb * 64 >= L) return;            // uniform: no row of this block is ever read
    int t = threadIdx.x;

    __shared__ float4 s_bx[NPAD + 16];

    for (int c = t; c < NPAD; c += 512)
        s_bx[c + (c >> 7)] = sbox[b * NPAD + c];
    __syncthreads();

    int r   = rb * 64 + (t & 63);        // lanes of a wave = 64 consecutive rows
    int seg = t >> 6;                    // word segment 0..7 (8 words each)
    float4 rbx = s_bx[r + (r >> 7)];
    float rar = (rbx.z - rbx.x) * (rbx.w - rbx.y);
    unsigned int* outp = mask + (((size_t)(b * NPAD + r)) << 6);

    for (int w = 0; w < 8; ++w) {
        int wi = (seg << 3) + w;
        unsigned int bits = 0u;
        int colbase = wi << 5;
        if (colbase + 31 > r && colbase < L) {
            #pragma unroll 8
            for (int c2 = 0; c2 < 32; ++c2) {
                int col = colbase + c2;
                float4 ob = s_bx[col + (col >> 7)];
                float oa = (ob.z - ob.x) * (ob.w - ob.y);
                float yy1 = fmaxf(rbx.x, ob.x), xx1 = fmaxf(rbx.y, ob.y);
                float yy2 = fminf(rbx.z, ob.z), xx2 = fminf(rbx.w, ob.w);
                float inter = fmaxf(yy2 - yy1, 0.f) * fmaxf(xx2 - xx1, 0.f);
                float iou = inter / (rar + oa - inter + 1e-8f);  // IEEE fdiv: exact vs ref
                bits |= (iou > IOU_T) ? (1u << c2) : 0u;
            }
        }
        outp[wi] = bits;
    }
}

// ---- walk: greedy over alive bitvector, scalar multi-extract find, 12-deep ----
// Find: one ballot -> peel words via ctzll, one readlane per WORD (not per
// candidate), pure-scalar bit extraction. Loads unconditional (r8 lesson).
__global__ __launch_bounds__(64) void walk_kernel(
        const int* __restrict__ Larr,
        const unsigned int* __restrict__ mask,
        int* __restrict__ klist,
        int* __restrict__ kcount) {
    int b = blockIdx.x;
    int lane = threadIdx.x;

    int L = Larr[b];
    int nset = L - (lane << 5);
    nset = nset < 0 ? 0 : (nset > 32 ? 32 : nset);
    unsigned int alive = (nset >= 32) ? 0xFFFFFFFFu
                        : ((nset <= 0) ? 0u : ((1u << nset) - 1u));

    const unsigned int* M = mask + ((size_t)b * NPAD) * MASK_WORDS;
    int* kl = klist + b * MAX_OUT;
    int kept = 0;

#define EXTRACT(cd)                                                          \
    {                                                                        \
        if (!aw && ne) {                                                     \
            int _w = (int)__builtin_ctzll(ne); ne &= ne - 1ull;              \
            wbase = _w << 5;                                                 \
            aw = (unsigned int)__builtin_amdgcn_readlane((int)alive, _w);    \
        }                                                                    \
        if (aw) { cd = wbase + (int)__builtin_ctz(aw); aw &= aw - 1u; }      \
    }
#define COMMIT(cd, rowd)                                                     \
    if (cd >= 0 && kept < MAX_OUT) {                                         \
        unsigned int _av =                                                   \
            (unsigned int)__builtin_amdgcn_readlane((int)alive, cd >> 5);    \
        if (_av & (1u << (cd & 31))) {                                       \
            if (lane == 0) kl[kept] = cd;                                    \
            kept++;                                                          \
            alive &= ~rowd;                                                  \
            if (lane == (cd >> 5)) alive &= ~(1u << (cd & 31));              \
        }                                                                    \
    }

    while (kept < MAX_OUT) {
        unsigned long long ne = __ballot(alive != 0u);
        if (!ne) break;
        unsigned int aw = 0u;
        int wbase = 0;
        int c0 = -1, c1 = -1, c2 = -1, c3 = -1, c4 = -1, c5 = -1,
            c6 = -1, c7 = -1, c8 = -1, c9 = -1, c10 = -1, c11 = -1;
        EXTRACT(c0); EXTRACT(c1); EXTRACT(c2); EXTRACT(c3);
        EXTRACT(c4); EXTRACT(c5); EXTRACT(c6); EXTRACT(c7);
        EXTRACT(c8); EXTRACT(c9); EXTRACT(c10); EXTRACT(c11);

        // safe addresses: missing slots alias c0 (valid row, never applied)
        int s1 = (c1 >= 0) ? c1 : c0;
        int s2 = (c2 >= 0) ? c2 : c0;
        int s3 = (c3 >= 0) ? c3 : c0;
        int s4 = (c4 >= 0) ? c4 : c0;
        int s5 = (c5 >= 0) ? c5 : c0;
        int s6 = (c6 >= 0) ? c6 : c0;
        int s7 = (c7 >= 0) ? c7 : c0;
        int s8 = (c8 >= 0) ? c8 : c0;
        int s9 = (c9 >= 0) ? c9 : c0;
        int s10 = (c10 >= 0) ? c10 : c0;
        int s11 = (c11 >= 0) ? c11 : c0;

        // 12 unconditional loads issue together; waits at first use
        unsigned int row0  = M[((size_t)c0  << 6) + lane];
        unsigned int row1  = M[((size_t)s1  << 6) + lane];
        unsigned int row2  = M[((size_t)s2  << 6) + lane];
        unsigned int row3  = M[((size_t)s3  << 6) + lane];
        unsigned int row4  = M[((size_t)s4  << 6) + lane];
        unsigned int row5  = M[((size_t)s5  << 6) + lane];
        unsigned int row6  = M[((size_t)s6  << 6) + lane];
        unsigned int row7  = M[((size_t)s7  << 6) + lane];
        unsigned int row8  = M[((size_t)s8  << 6) + lane];
        unsigned int row9  = M[((size_t)s9  << 6) + lane];
        unsigned int row10 = M[((size_t)s10 << 6) + lane];
        unsigned int row11 = M[((size_t)s11 << 6) + lane];

        // c0 always commits (global argmax of what's alive)
        if (lane == 0) kl[kept] = c0;
        kept++;
        alive &= ~row0;
        if (lane == (c0 >> 5)) alive &= ~(1u << (c0 & 31));

        COMMIT(c1, row1);  COMMIT(c2, row2);  COMMIT(c3, row3);
        COMMIT(c4, row4);  COMMIT(c5, row5);  COMMIT(c6, row6);
        COMMIT(c7, row7);  COMMIT(c8, row8);  COMMIT(c9, row9);
        COMMIT(c10, row10); COMMIT(c11, row11);
    }
#undef EXTRACT
#undef COMMIT

    if (lane == 0) kcount[b] = kept;
}

// ---------------- outputs: parallel gather + zero-fill ----------------
__global__ void out_kernel(const unsigned long long* __restrict__ skey,
                           const float4* __restrict__ sbox,
                           const int* __restrict__ klist,
                           const int* __restrict__ kcount,
                           const float* __restrict__ logits,
                           float* __restrict__ out) {
    int idx = blockIdx.x * blockDim.x + threadIdx.x;
    const int NB = BATCH * MAX_OUT * 5;        // 12000
    const int NS = BATCH * MAX_OUT * 2;        // 4800
    const int NL = BATCH * MAX_OUT * NCLS;     // 194400
    if (idx >= NB + NS + NL) return;

    if (idx < NB) {
        int b = idx / (MAX_OUT * 5);
        int rem = idx - b * (MAX_OUT * 5);
        int k = rem / 5, c = rem - 5 * k;
        float v = 0.f;
        if (k < kcount[b]) {
            if (c == 4) v = 1.f;
            else {
                float4 bx = sbox[b * NPAD + klist[b * MAX_OUT + k]];
                v = (c == 0) ? bx.x : (c == 1) ? bx.y : (c == 2) ? bx.z : bx.w;
            }
        }
        out[idx] = v;
    } else if (idx < NB + NS) {
        int j = idx - NB;
        int b = j / (MAX_OUT * 2);
        int rem = j - b * (MAX_OUT * 2);
        int k = rem >> 1, c = rem & 1;
        float v = 0.f;
        if (k < kcount[b]) {
            if (c) v = 1.f;
            else {
                unsigned long long key = skey[b * NPAD + klist[b * MAX_OUT + k]];
                v = __uint_as_float((unsigned int)(key >> 32));
            }
        }
        out[idx] = v;
    } else {
        int j = idx - NB - NS;
        int b = j / (MAX_OUT * NCLS);
        int rem = j - b * (MAX_OUT * NCLS);
        int k = rem / NCLS, c = rem - NCLS * k;
        float v = 0.f;
        if (k < kcount[b]) {
            unsigned long long key = skey[b * NPAD + klist[b * MAX_OUT + k]];
            unsigned int orig = 0xFFFFFFFFu - (unsigned int)key;
            v = logits[((long)b * NBOX + orig) * NCLS + c];
        }
        out[idx] = v;
    }
}

extern "C" void kernel_launch(void* const* d_in, const int* in_sizes, int n_in,
                              void* d_out, int out_size, void* d_ws, size_t ws_size,
                              hipStream_t stream) {
    const float* deltas    = (const float*)d_in[0];
    const float* logits    = (const float*)d_in[1];
    const float* proposals = (const float*)d_in[2];
    float* out = (float*)d_out;

    char* ws = (char*)d_ws;
    float4* ws_boxes  = (float4*)(ws + WS_BOXES);
    float*  ws_scores = (float*)(ws + WS_SCORES);
    unsigned long long* ws_skey = (unsigned long long*)(ws + WS_SKEY);
    float4* ws_sbox   = (float4*)(ws + WS_SBOX);
    int*    ws_Larr   = (int*)(ws + WS_LARR);
    int*    ws_klist  = (int*)(ws + WS_KLIST);
    int*    ws_kcount = (int*)(ws + WS_KCOUNT);
    unsigned int* ws_mask = (unsigned int*)(ws + WS_MASK);

    prep_kernel<<<(BATCH * NBOX + 255) / 256, 256, 0, stream>>>(
        deltas, logits, proposals, ws_boxes, ws_scores, ws_Larr);
    rank_kernel<<<BATCH * (NPAD / 64), 512, 0, stream>>>(
        ws_scores, ws_boxes, ws_skey, ws_sbox, ws_Larr);
    mask_kernel<<<BATCH * (NPAD / 64), 512, 0, stream>>>(
        ws_sbox, ws_Larr, ws_mask);
    walk_kernel<<<BATCH, 64, 0, stream>>>(
        ws_Larr, ws_mask, ws_klist, ws_kcount);
    int total_out = BATCH * MAX_OUT * (5 + 2 + NCLS);
    out_kernel<<<(total_out + 255) / 256, 256, 0, stream>>>(
        ws_skey, ws_sbox, ws_klist, ws_kcount, logits, out);
}